// Round 2
// baseline (118.324 us; speedup 1.0000x reference)
//
#include <hip/hip_runtime.h>
#include <hip/hip_bf16.h>
#include <stdint.h>

#define B_   4
#define H_   56
#define W_   56
#define C_   256
#define CR   64
#define G_   16
#define CG   16
#define KS   7
#define KK   49
#define PADR 3
#define NPX  (B_*H_*W_)   // 12544

typedef __attribute__((ext_vector_type(8))) short bf16x8;
typedef __attribute__((ext_vector_type(4))) float f32x4;
typedef __attribute__((ext_vector_type(2))) float f32x2;

__device__ __forceinline__ uint32_t f2bf(float f) {          // RNE fp32->bf16 bits
    uint32_t x = __float_as_uint(f);
    return (x + 0x7fffu + ((x >> 16) & 1u)) >> 16;
}
__device__ __forceinline__ uint32_t pkbf(float a, float b) { // packed RNE: v_cvt_pk_bf16_f32
    union { __hip_bfloat162 h; uint32_t u; } c;
    c.h = __float22bfloat162_rn(make_float2(a, b));
    return c.u;                                              // a lo16, b hi16
}
__device__ __forceinline__ float blo(uint32_t w) { return __uint_as_float(w << 16); }
__device__ __forceinline__ float bhi(uint32_t w) { return __uint_as_float(w & 0xffff0000u); }

union U4V { uint4 u; bf16x8 v; };

// ---------- K0: prepack weights into MFMA B-frag layout (bf16), fold BN ----------
// frag layout for mfma_f32_16x16x32_bf16 B: lane holds B[k=(lane>>4)*8+j][n=lane&15], j=0..7
__global__ __launch_bounds__(256) void k0_prepack(
        const float* __restrict__ wr, const float* __restrict__ wspan,
        const float* __restrict__ gamma, const float* __restrict__ beta,
        const float* __restrict__ mean, const float* __restrict__ var,
        uint16_t* __restrict__ wrp, uint16_t* __restrict__ wpp,
        float* __restrict__ scale, float* __restrict__ shift) {
    int idx = blockIdx.x * 256 + threadIdx.x;   // 0..65535
    {   // w_span pack: idx = g*4096 + kb*2048 + nb*512 + lane*8 + j
        int j = idx & 7, lane = (idx >> 3) & 63, nb = (idx >> 9) & 3,
            kb = (idx >> 11) & 1, g = idx >> 12;
        int k = kb * 32 + (lane >> 4) * 8 + j;
        int n = nb * 16 + (lane & 15);
        float v = (n < KK) ? wspan[k * (KK * G_) + g * KK + n] : 0.f;
        wpp[idx] = (uint16_t)f2bf(v);
    }
    if (idx < 16384) {  // w_reduce pack (dual use: B-frag of x@wr, A-frag of wrT@xT)
        int j = idx & 7, lane = (idx >> 3) & 63, nb = (idx >> 9) & 3, kb = idx >> 11;
        int k = kb * 32 + (lane >> 4) * 8 + j;
        int n = nb * 16 + (lane & 15);
        wrp[idx] = (uint16_t)f2bf(wr[k * CR + n]);
    }
    if (idx < CR) {
        float s = gamma[idx] * rsqrtf(var[idx] + 1e-3f);
        scale[idx] = s;
        shift[idx] = beta[idx] - mean[idx] * s;
    }
}

// ---------- fused: x-stage + GEMM1(r) + GEMM2(kgen) + involution, all in one block ----------
#define TS   14          // output tile edge
#define HS   20          // TS + KS - 1
#define XSP  21          // xs row pitch in 32B slots (672B%128=32 -> bank quads rotate per row)
#define KGW  56          // u16 per kg row: 7 kh * 8 slots (7 taps + 1 pad)

#define LDS_XS   0                      // xs: 420 slots * 32B = 13440 B
#define LDS_WK   13440                  // wrp copy 32768 B; kg (21952 B) aliases after GEMM1
#define LDS_RB   (13440 + 32768)        // rbuf: 196 rows * 128 B = 25088 B (XOR-swizzled)
#define LDS_TOT  (13440 + 32768 + 25088)  // 71296 B -> 2 blocks/CU

__global__ __launch_bounds__(256, 2) void k_fused(
        const float* __restrict__ x, const uint16_t* __restrict__ wrp,
        const uint16_t* __restrict__ wpp,
        const float* __restrict__ scale, const float* __restrict__ shift,
        const float* __restrict__ bspan, float* __restrict__ out) {
    __shared__ __align__(16) uint8_t lds[LDS_TOT];
    uint16_t* xs   = (uint16_t*)(lds + LDS_XS);
    uint16_t* wrpL = (uint16_t*)(lds + LDS_WK);
    uint16_t* kg   = (uint16_t*)(lds + LDS_WK);   // aliases wrpL (after barrier 2)
    uint8_t*  rb   = lds + LDS_RB;

    int tid  = threadIdx.x;
    int tile = blockIdx.x, g = blockIdx.y, b = blockIdx.z;
    int ty0 = (tile >> 2) * TS, tx0 = (tile & 3) * TS;
    int lane = tid & 63, w = tid >> 6;

    // ---- phase A: stage x halo (fp32 -> bf16) + linear copy of packed w_reduce ----
    #pragma unroll
    for (int pass = 0; pass < 2; ++pass) {
        int i = tid + pass * 256;
        if (i < HS * HS) {
            int py = i / HS, px = i % HS;
            int gy = ty0 + py - PADR, gx = tx0 + px - PADR;
            uint4 wA = make_uint4(0, 0, 0, 0), wB = wA;
            if (gy >= 0 && gy < H_ && gx >= 0 && gx < W_) {
                const float* xp = x + (((size_t)(b * H_ + gy)) * W_ + gx) * C_ + g * CG;
                float4 a0 = *(const float4*)(xp);
                float4 a1 = *(const float4*)(xp + 4);
                float4 a2 = *(const float4*)(xp + 8);
                float4 a3 = *(const float4*)(xp + 12);
                wA = make_uint4(pkbf(a0.x, a0.y), pkbf(a0.z, a0.w),
                                pkbf(a1.x, a1.y), pkbf(a1.z, a1.w));
                wB = make_uint4(pkbf(a2.x, a2.y), pkbf(a2.z, a2.w),
                                pkbf(a3.x, a3.y), pkbf(a3.z, a3.w));
            }
            uint16_t* dst = xs + (py * XSP + px) * 16;
            *(uint4*)(dst + 0) = wA;
            *(uint4*)(dst + 8) = wB;
        }
    }
    #pragma unroll
    for (int q = 0; q < 8; ++q) {       // 32 KB coalesced memcpy, no scatter
        int f = q * 256 + tid;          // uint4 index 0..2047
        *(uint4*)(wrpL + f * 8) = *(const uint4*)(wrp + f * 8);
    }
    __syncthreads();                    // B1

    // ---- phase B: GEMM1 swapped -> D1[ch][pix] = sum_k wr[k][ch] * x[pix][k] ----
    // lane holds pixel = lane&15 and channels rq..rq+3 per 16-ch tile -> pairable bf16 writes
    int rq = (lane >> 4) * 4;
    float s16[16], sh16[16];
    #pragma unroll
    for (int mtc = 0; mtc < 4; ++mtc)
        #pragma unroll
        for (int rg = 0; rg < 4; ++rg) {
            int ch = mtc * 16 + rq + rg;
            s16[mtc * 4 + rg]  = scale[ch];
            sh16[mtc * 4 + rg] = shift[ch];
        }
    for (int nt = w; nt < 13; nt += 4) {            // 13 pixel n-tiles over 4 waves
        int m  = nt * 16 + (lane & 15);
        int mm = m < 196 ? m : 195;
        int ly = mm / TS, lx = mm % TS;
        size_t pix = ((size_t)(b * H_ + ty0 + ly)) * W_ + (tx0 + lx);
        const float* xrow = x + pix * C_ + (lane >> 4) * 8;
        f32x4 acc[4] = {{0,0,0,0},{0,0,0,0},{0,0,0,0},{0,0,0,0}};
        #pragma unroll
        for (int kb = 0; kb < 8; ++kb) {
            float4 a0 = *(const float4*)(xrow + kb * 32);
            float4 a1 = *(const float4*)(xrow + kb * 32 + 4);
            U4V xf;
            xf.u = make_uint4(pkbf(a0.x, a0.y), pkbf(a0.z, a0.w),
                              pkbf(a1.x, a1.y), pkbf(a1.z, a1.w));
            const uint16_t* wbase = wrpL + kb * 2048 + lane * 8;  // lane*16B: conflict-free
            #pragma unroll
            for (int mtc = 0; mtc < 4; ++mtc) {
                bf16x8 af = *(const bf16x8*)(wbase + mtc * 512);  // A = wrT frag
                acc[mtc] = __builtin_amdgcn_mfma_f32_16x16x32_bf16(af, xf.v, acc[mtc], 0, 0, 0);
            }
        }
        if (m < 196) {                   // BN + ReLU + pack pairs, 8B swizzled LDS writes
            #pragma unroll
            for (int mtc = 0; mtc < 4; ++mtc) {
                float v0 = fmaf(acc[mtc][0], s16[mtc*4+0], sh16[mtc*4+0]); v0 = v0 > 0.f ? v0 : 0.f;
                float v1 = fmaf(acc[mtc][1], s16[mtc*4+1], sh16[mtc*4+1]); v1 = v1 > 0.f ? v1 : 0.f;
                float v2 = fmaf(acc[mtc][2], s16[mtc*4+2], sh16[mtc*4+2]); v2 = v2 > 0.f ? v2 : 0.f;
                float v3 = fmaf(acc[mtc][3], s16[mtc*4+3], sh16[mtc*4+3]); v3 = v3 > 0.f ? v3 : 0.f;
                int c2  = mtc * 32 + rq * 2;         // byte col of ch pair base
                int blk = c2 >> 4, within = c2 & 15; // 8B write stays in one 16B block
                uint32_t off = (uint32_t)m * 128 + (((blk ^ (m & 7)) << 4) | within);
                *(uint2*)(rb + off) = make_uint2(pkbf(v0, v1), pkbf(v2, v3));
            }
        }
    }

    // preload w_span frags + bias (global, independent of LDS -> overlaps barrier)
    bf16x8 bfr[2][4];
    const uint16_t* wb2 = wpp + g * 4096 + lane * 8;
    #pragma unroll
    for (int kb = 0; kb < 2; ++kb)
        #pragma unroll
        for (int nb = 0; nb < 4; ++nb)
            bfr[kb][nb] = *(const bf16x8*)(wb2 + kb * 2048 + nb * 512);
    float bias[4];
    #pragma unroll
    for (int nb = 0; nb < 4; ++nb) {
        int n = nb * 16 + (lane & 15);
        bias[nb] = (n < KK) ? bspan[g * KK + n] : 0.f;
    }
    __syncthreads();                    // B2: rbuf complete; kg may now clobber wrpL

    // ---- phase C: GEMM2 kgen: kg(196x49) = r(196x64) @ wspan_g(64x49) + bias ----
    for (int mi = 0; mi < 4; ++mi) {
        int mt = mi * 4 + w;            // 13 row-tiles over 4 waves
        if (mt < 13) {
            int m  = mt * 16 + (lane & 15);
            int mm = m < 196 ? m : 195;
            int q  = lane >> 4;
            uint32_t offA = (uint32_t)mm * 128 + (uint32_t)(((q     ^ (mm & 7)) << 4));
            uint32_t offB = (uint32_t)mm * 128 + (uint32_t)((((4+q) ^ (mm & 7)) << 4));
            bf16x8 a0 = *(const bf16x8*)(rb + offA);   // r[pix][ch 0..31 slice]
            bf16x8 a1 = *(const bf16x8*)(rb + offB);   // r[pix][ch 32..63 slice]
            f32x4 acc[4];
            #pragma unroll
            for (int nb = 0; nb < 4; ++nb)
                acc[nb] = (f32x4){bias[nb], bias[nb], bias[nb], bias[nb]};
            #pragma unroll
            for (int nb = 0; nb < 4; ++nb) {
                acc[nb] = __builtin_amdgcn_mfma_f32_16x16x32_bf16(a0, bfr[0][nb], acc[nb], 0, 0, 0);
                acc[nb] = __builtin_amdgcn_mfma_f32_16x16x32_bf16(a1, bfr[1][nb], acc[nb], 0, 0, 0);
            }
            int row = mt * 16 + (lane >> 4) * 4;
            if (row < 196) {
                #pragma unroll
                for (int nb = 0; nb < 4; ++nb) {
                    int n = nb * 16 + (lane & 15);
                    if (n < KK) {
                        int slot = n + n / 7;        // per-kh padded: kh*8 + kw
                        #pragma unroll
                        for (int rg = 0; rg < 4; ++rg) {
                            int rr  = row + rg;
                            int rho = (rr >> 1) + (rr & 1) * 98;  // even/odd row split
                            kg[rho * KGW + slot] = (uint16_t)f2bf(acc[nb][rg]);
                        }
                    }
                }
            }
        }
    }
    __syncthreads();                    // B3

    // ---- phase D: involution: 196 threads = (pixel-pair, 8-ch half) ----
    if (tid < 196) {
        int p = tid >> 1, h = tid & 1;
        int ty = p / 7, tx = (p % 7) * 2;
        const uint16_t* kgL = kg + p * KGW;          // even pixels: consecutive rows
        const uint16_t* kgR = kg + (98 + p) * KGW;   // odd pixels

        f32x2 accL[4] = {{0,0},{0,0},{0,0},{0,0}};
        f32x2 accR[4] = {{0,0},{0,0},{0,0},{0,0}};
        #pragma unroll
        for (int kh = 0; kh < KS; ++kh) {
            uint4 aL = *(const uint4*)(kgL + kh * 8);
            uint4 aR = *(const uint4*)(kgR + kh * 8);
            const uint32_t kwL[4] = {aL.x, aL.y, aL.z, aL.w};
            const uint32_t kwR[4] = {aR.x, aR.y, aR.z, aR.w};
            const uint16_t* xrow = xs + ((ty + kh) * XSP + tx) * 16 + h * 8;
            #pragma unroll
            for (int j = 0; j < 8; ++j) {            // union of both 7-tap windows
                uint4 xw = *(const uint4*)(xrow + j * 16);
                f32x2 x0 = {blo(xw.x), bhi(xw.x)};
                f32x2 x1 = {blo(xw.y), bhi(xw.y)};
                f32x2 x2 = {blo(xw.z), bhi(xw.z)};
                f32x2 x3 = {blo(xw.w), bhi(xw.w)};
                if (j < 7) {
                    float kv = (j & 1) ? bhi(kwL[j >> 1]) : blo(kwL[j >> 1]);
                    f32x2 kL = {kv, kv};
                    accL[0] = __builtin_elementwise_fma(kL, x0, accL[0]);
                    accL[1] = __builtin_elementwise_fma(kL, x1, accL[1]);
                    accL[2] = __builtin_elementwise_fma(kL, x2, accL[2]);
                    accL[3] = __builtin_elementwise_fma(kL, x3, accL[3]);
                }
                if (j > 0) {
                    int t = j - 1;
                    float kv = (t & 1) ? bhi(kwR[t >> 1]) : blo(kwR[t >> 1]);
                    f32x2 kR = {kv, kv};
                    accR[0] = __builtin_elementwise_fma(kR, x0, accR[0]);
                    accR[1] = __builtin_elementwise_fma(kR, x1, accR[1]);
                    accR[2] = __builtin_elementwise_fma(kR, x2, accR[2]);
                    accR[3] = __builtin_elementwise_fma(kR, x3, accR[3]);
                }
            }
        }
        size_t pixL = ((size_t)(b * H_ + ty0 + ty)) * W_ + (tx0 + tx);
        float* opL = out + pixL * C_ + g * CG + h * 8;
        float* opR = opL + C_;
        *(float4*)(opL + 0) = make_float4(accL[0].x, accL[0].y, accL[1].x, accL[1].y);
        *(float4*)(opL + 4) = make_float4(accL[2].x, accL[2].y, accL[3].x, accL[3].y);
        *(float4*)(opR + 0) = make_float4(accR[0].x, accR[0].y, accR[1].x, accR[1].y);
        *(float4*)(opR + 4) = make_float4(accR[2].x, accR[2].y, accR[3].x, accR[3].y);
    }
}

extern "C" void kernel_launch(void* const* d_in, const int* in_sizes, int n_in,
                              void* d_out, int out_size, void* d_ws, size_t ws_size,
                              hipStream_t stream) {
    const float* x        = (const float*)d_in[0];
    const float* w_reduce = (const float*)d_in[1];
    const float* gamma    = (const float*)d_in[2];
    const float* beta     = (const float*)d_in[3];
    const float* mean     = (const float*)d_in[4];
    const float* var      = (const float*)d_in[5];
    const float* w_span   = (const float*)d_in[6];
    const float* b_span   = (const float*)d_in[7];
    float* out = (float*)d_out;

    uint8_t* ws = (uint8_t*)d_ws;
    uint16_t* wrp   = (uint16_t*)(ws + 0);          // 32768 B
    uint16_t* wpp   = (uint16_t*)(ws + 32768);      // 131072 B
    float*    scale = (float*)   (ws + 163840);     // 256 B
    float*    shift = (float*)   (ws + 164096);     // 256 B

    hipLaunchKernelGGL(k0_prepack, dim3(256), dim3(256), 0, stream,
                       w_reduce, w_span, gamma, beta, mean, var,
                       wrp, wpp, scale, shift);
    hipLaunchKernelGGL(k_fused, dim3(16, 16, B_), dim3(256), 0, stream,
                       x, wrp, wpp, scale, shift, b_span, out);
}

// Round 3
// 97.769 us; speedup vs baseline: 1.2102x; 1.2102x over previous
//
#include <hip/hip_runtime.h>
#include <hip/hip_bf16.h>
#include <stdint.h>

#define B_   4
#define H_   56
#define W_   56
#define C_   256
#define CR   64
#define G_   16
#define CG   16
#define KS   7
#define KK   49
#define PADR 3
#define NPX  (B_*H_*W_)   // 12544

typedef __attribute__((ext_vector_type(8))) short bf16x8;
typedef __attribute__((ext_vector_type(4))) float f32x4;
typedef __attribute__((ext_vector_type(2))) float f32x2;

__device__ __forceinline__ uint32_t f2bf(float f) {          // RNE fp32->bf16 bits
    uint32_t x = __float_as_uint(f);
    return (x + 0x7fffu + ((x >> 16) & 1u)) >> 16;
}
__device__ __forceinline__ uint32_t pkbf(float a, float b) { // packed RNE: v_cvt_pk_bf16_f32
    union { __hip_bfloat162 h; uint32_t u; } c;
    c.h = __float22bfloat162_rn(make_float2(a, b));
    return c.u;                                              // a lo16, b hi16
}
__device__ __forceinline__ float blo(uint32_t w) { return __uint_as_float(w << 16); }
__device__ __forceinline__ float bhi(uint32_t w) { return __uint_as_float(w & 0xffff0000u); }

union U4V { uint4 u; bf16x8 v; };

// ---------- K0: prepack weights into MFMA B-frag layout (bf16), fold BN ----------
// B-frag for mfma_f32_16x16x32_bf16: lane holds B[k=(lane>>4)*8+j][n=lane&15], j=0..7
__global__ __launch_bounds__(256) void k0_prepack(
        const float* __restrict__ wr, const float* __restrict__ wspan,
        const float* __restrict__ gamma, const float* __restrict__ beta,
        const float* __restrict__ mean, const float* __restrict__ var,
        uint16_t* __restrict__ wrp, uint16_t* __restrict__ wpp,
        float* __restrict__ scale, float* __restrict__ shift) {
    int idx = blockIdx.x * 256 + threadIdx.x;   // 0..65535
    {   // w_span pack: idx = g*4096 + kb*2048 + nb*512 + lane*8 + j
        int j = idx & 7, lane = (idx >> 3) & 63, nb = (idx >> 9) & 3,
            kb = (idx >> 11) & 1, g = idx >> 12;
        int k = kb * 32 + (lane >> 4) * 8 + j;
        int n = nb * 16 + (lane & 15);
        float v = (n < KK) ? wspan[k * (KK * G_) + g * KK + n] : 0.f;
        wpp[idx] = (uint16_t)f2bf(v);
    }
    if (idx < 16384) {  // w_reduce pack
        int j = idx & 7, lane = (idx >> 3) & 63, nb = (idx >> 9) & 3, kb = idx >> 11;
        int k = kb * 32 + (lane >> 4) * 8 + j;
        int n = nb * 16 + (lane & 15);
        wrp[idx] = (uint16_t)f2bf(wr[k * CR + n]);
    }
    if (idx < CR) {
        float s = gamma[idx] * rsqrtf(var[idx] + 1e-3f);
        scale[idx] = s;
        shift[idx] = beta[idx] - mean[idx] * s;
    }
}

// ---------- K1: r = relu(bn(x @ w_reduce)) via MFMA + emit x as bf16 ----------
__global__ __launch_bounds__(256) void k1_reduce(
        const float* __restrict__ x, const uint16_t* __restrict__ wrp,
        const float* __restrict__ scale, const float* __restrict__ shift,
        uint16_t* __restrict__ r, uint16_t* __restrict__ xbf) {
    int tid = threadIdx.x;
    int lane = tid & 63, w = tid >> 6;
    int mt = blockIdx.x * 4 + w;                 // 784 row-tiles of 16 pixels
    int pix = mt * 16 + (lane & 15);             // A-frag: m = lane&15
    int ko = (lane >> 4) * 8;                    // k-offset within 32-block
    const float* xrow = x + (size_t)pix * C_ + ko;
    f32x4 acc[4] = {{0,0,0,0},{0,0,0,0},{0,0,0,0},{0,0,0,0}};
    for (int kb = 0; kb < 8; ++kb) {             // K = 256 in steps of 32
        float4 a0 = *(const float4*)(xrow + kb * 32);
        float4 a1 = *(const float4*)(xrow + kb * 32 + 4);
        U4V af;
        af.u = make_uint4(pkbf(a0.x, a0.y), pkbf(a0.z, a0.w),
                          pkbf(a1.x, a1.y), pkbf(a1.z, a1.w));
        // bf16 copy of x for K2 staging
        *(uint4*)(xbf + (size_t)pix * C_ + ko + kb * 32) = af.u;
        const uint16_t* wb = wrp + kb * 2048 + lane * 8;
        #pragma unroll
        for (int nb = 0; nb < 4; ++nb) {
            bf16x8 bf_ = *(const bf16x8*)(wb + nb * 512);
            acc[nb] = __builtin_amdgcn_mfma_f32_16x16x32_bf16(af.v, bf_, acc[nb], 0, 0, 0);
        }
    }
    // C layout: col=lane&15 (channel), row=(lane>>4)*4+reg (pixel)
    int rq = (lane >> 4) * 4;
    #pragma unroll
    for (int nb = 0; nb < 4; ++nb) {
        int d = nb * 16 + (lane & 15);
        float s = scale[d], sh = shift[d];
        #pragma unroll
        for (int rg = 0; rg < 4; ++rg) {
            float v = fmaf(acc[nb][rg], s, sh);
            v = v > 0.f ? v : 0.f;
            r[(size_t)(mt * 16 + rq + rg) * CR + d] = (uint16_t)f2bf(v);
        }
    }
}

// ---------- K2: kgen (MFMA) + involution, one block per (tile, group, batch) ----------
#define TS   14          // output tile edge
#define HS   20          // TS + KS - 1
#define XSP  21          // xs row pitch in 32B slots: 672B%128=32 -> bank quads rotate per row
#define KGW  56          // u16 per kg row: 7 kh * 8 slots (7 taps + 1 pad), 112B pitch

__global__ __launch_bounds__(256, 4) void k2_involution(
        const uint16_t* __restrict__ xbf, const uint16_t* __restrict__ r,
        const uint16_t* __restrict__ wpp, const float* __restrict__ bspan,
        float* __restrict__ out) {
    __shared__ __align__(16) uint16_t xs[420 * 16];        // 13440 B (pitch-21 rows)
    __shared__ __align__(16) uint16_t kg[196 * KGW];       // 21952 B; rho = (pix>>1)+(pix&1)*98

    int tid  = threadIdx.x;
    int tile = blockIdx.x, g = blockIdx.y, b = blockIdx.z;
    int ty0 = (tile >> 2) * TS, tx0 = (tile & 3) * TS;

    // ---- stage x group-slice (with halo) into LDS: raw bf16, no conversion ----
    #pragma unroll
    for (int pass = 0; pass < 2; ++pass) {
        int i = tid + pass * 256;
        if (i < HS * HS) {
            int py = i / HS, px = i % HS;
            int gy = ty0 + py - PADR, gx = tx0 + px - PADR;
            uint4 wA = make_uint4(0, 0, 0, 0), wB = wA;
            if (gy >= 0 && gy < H_ && gx >= 0 && gx < W_) {
                const uint16_t* xp = xbf + (((size_t)(b * H_ + gy)) * W_ + gx) * C_ + g * CG;
                wA = *(const uint4*)(xp);
                wB = *(const uint4*)(xp + 8);
            }
            uint16_t* dst = xs + (py * XSP + px) * 16;     // pitch-21 slots
            *(uint4*)(dst + 0) = wA;
            *(uint4*)(dst + 8) = wB;
        }
    }

    // ---- kgen via MFMA: kg(196x49) = r_tile(196x64) @ wspan_g(64x49) + bias ----
    int lane = tid & 63, w = tid >> 6;
    bf16x8 bfr[2][4];
    const uint16_t* wb = wpp + g * 4096 + lane * 8;
    #pragma unroll
    for (int kb = 0; kb < 2; ++kb)
        #pragma unroll
        for (int nb = 0; nb < 4; ++nb)
            bfr[kb][nb] = *(const bf16x8*)(wb + kb * 2048 + nb * 512);
    float bias[4];
    #pragma unroll
    for (int nb = 0; nb < 4; ++nb) {
        int n = nb * 16 + (lane & 15);
        bias[nb] = (n < KK) ? bspan[g * KK + n] : 0.f;
    }
    for (int mi = 0; mi < 4; ++mi) {
        int mt = mi * 4 + w;                    // 13 row-tiles over 4 waves
        if (mt < 13) {
            int m  = mt * 16 + (lane & 15);
            int mm = m < 196 ? m : 195;         // pad rows: valid mem, ignored later
            int ly = mm / TS, lx = mm % TS;
            size_t pix = ((size_t)(b * H_ + ty0 + ly)) * W_ + (tx0 + lx);
            const uint16_t* rp = r + pix * CR + (lane >> 4) * 8;
            bf16x8 a0 = *(const bf16x8*)(rp);
            bf16x8 a1 = *(const bf16x8*)(rp + 32);
            f32x4 acc[4];
            #pragma unroll
            for (int nb = 0; nb < 4; ++nb)
                acc[nb] = (f32x4){bias[nb], bias[nb], bias[nb], bias[nb]};
            #pragma unroll
            for (int nb = 0; nb < 4; ++nb) {
                acc[nb] = __builtin_amdgcn_mfma_f32_16x16x32_bf16(a0, bfr[0][nb], acc[nb], 0, 0, 0);
                acc[nb] = __builtin_amdgcn_mfma_f32_16x16x32_bf16(a1, bfr[1][nb], acc[nb], 0, 0, 0);
            }
            int row = mt * 16 + (lane >> 4) * 4;
            if (row < 196) {                    // skip pad rows entirely
                #pragma unroll
                for (int nb = 0; nb < 4; ++nb) {
                    int n = nb * 16 + (lane & 15);
                    if (n < KK) {
                        int slot = n + n / 7;   // per-kh padded: kh*8 + kw
                        #pragma unroll
                        for (int rg = 0; rg < 4; ++rg) {
                            int rr  = row + rg;
                            int rho = (rr >> 1) + (rr & 1) * 98;  // even/odd row split
                            kg[rho * KGW + slot] = (uint16_t)f2bf(acc[nb][rg]);
                        }
                    }
                }
            }
        }
    }
    __syncthreads();

    // ---- involution: 196 threads = (pixel-pair, 8-ch half); adjacent px share xs reads ----
    if (tid < 196) {
        int p = tid >> 1, h = tid & 1;          // pair 0..97, channel half 0/1
        int ty = p / 7, tx = (p % 7) * 2;       // left pixel index = 2p
        const uint16_t* kgL = kg + p * KGW;         // even pixels: consecutive rows
        const uint16_t* kgR = kg + (98 + p) * KGW;  // odd pixels: consecutive rows

        f32x2 accL[4] = {{0,0},{0,0},{0,0},{0,0}};
        f32x2 accR[4] = {{0,0},{0,0},{0,0},{0,0}};
        #pragma unroll
        for (int kh = 0; kh < KS; ++kh) {
            uint4 aL = *(const uint4*)(kgL + kh * 8);   // taps kh*7..kh*7+6 (+pad)
            uint4 aR = *(const uint4*)(kgR + kh * 8);
            const uint32_t kwL[4] = {aL.x, aL.y, aL.z, aL.w};
            const uint32_t kwR[4] = {aR.x, aR.y, aR.z, aR.w};
            const uint16_t* xrow = xs + ((ty + kh) * XSP + tx) * 16 + h * 8;
            #pragma unroll
            for (int j = 0; j < 8; ++j) {       // union of both 7-tap windows
                uint4 xw = *(const uint4*)(xrow + j * 16);   // 8 bf16 channels
                float kvL = 0.f, kvR = 0.f;
                if (j < 7) kvL = (j & 1) ? bhi(kwL[j >> 1]) : blo(kwL[j >> 1]);
                if (j > 0) { int t = j - 1; kvR = (t & 1) ? bhi(kwR[t >> 1]) : blo(kwR[t >> 1]); }
                f32x2 kL = {kvL, kvL}, kR = {kvR, kvR};
                f32x2 x0 = {blo(xw.x), bhi(xw.x)};
                f32x2 x1 = {blo(xw.y), bhi(xw.y)};
                f32x2 x2 = {blo(xw.z), bhi(xw.z)};
                f32x2 x3 = {blo(xw.w), bhi(xw.w)};
                accL[0] = __builtin_elementwise_fma(kL, x0, accL[0]);
                accL[1] = __builtin_elementwise_fma(kL, x1, accL[1]);
                accL[2] = __builtin_elementwise_fma(kL, x2, accL[2]);
                accL[3] = __builtin_elementwise_fma(kL, x3, accL[3]);
                accR[0] = __builtin_elementwise_fma(kR, x0, accR[0]);
                accR[1] = __builtin_elementwise_fma(kR, x1, accR[1]);
                accR[2] = __builtin_elementwise_fma(kR, x2, accR[2]);
                accR[3] = __builtin_elementwise_fma(kR, x3, accR[3]);
            }
        }
        size_t pixL = ((size_t)(b * H_ + ty0 + ty)) * W_ + (tx0 + tx);
        float* opL = out + pixL * C_ + g * CG + h * 8;
        float* opR = opL + C_;
        *(float4*)(opL + 0) = make_float4(accL[0].x, accL[0].y, accL[1].x, accL[1].y);
        *(float4*)(opL + 4) = make_float4(accL[2].x, accL[2].y, accL[3].x, accL[3].y);
        *(float4*)(opR + 0) = make_float4(accR[0].x, accR[0].y, accR[1].x, accR[1].y);
        *(float4*)(opR + 4) = make_float4(accR[2].x, accR[2].y, accR[3].x, accR[3].y);
    }
}

extern "C" void kernel_launch(void* const* d_in, const int* in_sizes, int n_in,
                              void* d_out, int out_size, void* d_ws, size_t ws_size,
                              hipStream_t stream) {
    const float* x        = (const float*)d_in[0];
    const float* w_reduce = (const float*)d_in[1];
    const float* gamma    = (const float*)d_in[2];
    const float* beta     = (const float*)d_in[3];
    const float* mean     = (const float*)d_in[4];
    const float* var      = (const float*)d_in[5];
    const float* w_span   = (const float*)d_in[6];
    const float* b_span   = (const float*)d_in[7];
    float* out = (float*)d_out;

    uint8_t* ws = (uint8_t*)d_ws;
    uint16_t* r_ws  = (uint16_t*)(ws + 0);          // 1605632 B
    uint16_t* wrp   = (uint16_t*)(ws + 1605632);    // 32768 B
    uint16_t* wpp   = (uint16_t*)(ws + 1638400);    // 131072 B
    float*    scale = (float*)   (ws + 1769472);    // 256 B
    float*    shift = (float*)   (ws + 1769728);    // 256 B
    uint16_t* xbf   = (uint16_t*)(ws + 1769984);    // 6422528 B

    hipLaunchKernelGGL(k0_prepack, dim3(256), dim3(256), 0, stream,
                       w_reduce, w_span, gamma, beta, mean, var,
                       wrp, wpp, scale, shift);
    hipLaunchKernelGGL(k1_reduce, dim3(NPX / 64), dim3(256), 0, stream,
                       x, wrp, scale, shift, r_ws, xbf);
    hipLaunchKernelGGL(k2_involution, dim3(16, 16, B_), dim3(256), 0, stream,
                       xbf, r_ws, wpp, b_span, out);
}